// Round 1
// baseline (419.582 us; speedup 1.0000x reference)
//
#include <hip/hip_runtime.h>
#include <stdint.h>

typedef unsigned short u16;
typedef __attribute__((ext_vector_type(8))) short v8s;
typedef __attribute__((ext_vector_type(4))) float v4f;

// ---------- helpers ----------
__device__ __forceinline__ u16 f2bf(float f) {
  uint32_t x = __float_as_uint(f);
  return (u16)((x + 0x7fffu + ((x >> 16) & 1u)) >> 16);
}
__device__ __forceinline__ float bf2f(u16 u) {
  return __uint_as_float(((uint32_t)u) << 16);
}
__device__ __forceinline__ float sigf(float x) { return 1.f / (1.f + __expf(-x)); }

__device__ __forceinline__ v4f mfma16(v8s a, v8s b, v4f c) {
  return __builtin_amdgcn_mfma_f32_16x16x32_bf16(a, b, c, 0, 0, 0);
}

// async global->LDS, 16B per lane; lds dest must be wave-uniform (HW adds lane*16)
__device__ __forceinline__ void gll16(const u16* src, u16* ldsdst) {
  __builtin_amdgcn_global_load_lds(
      reinterpret_cast<__attribute__((address_space(1))) uint32_t*>(
          reinterpret_cast<uintptr_t>(src)),
      reinterpret_cast<__attribute__((address_space(3))) uint32_t*>(
          reinterpret_cast<uintptr_t>(ldsdst)),
      16, 0, 0);
}

// stage a 64x64 bf16 tile (row-major [64][64]) from g[row0.., col0..] with leading dim ld
__device__ __forceinline__ void stage64(const u16* g, int ld, int row0, int col0,
                                        u16* lds, int wid, int lane) {
  const int rbase = wid * 16;
  const int r0 = rbase + (lane >> 3);
  const int cs = (lane & 7) * 8;
  gll16(g + (size_t)(row0 + r0) * ld + col0 + cs, lds + rbase * 64);
  gll16(g + (size_t)(row0 + r0 + 8) * ld + col0 + cs, lds + (rbase + 8) * 64);
}

// MFMA A/B fragment read from [.][64] tile: row=rowbase+(lane&15), k=s*32+(lane>>4)*8
__device__ __forceinline__ v8s fragAB(const u16* lds, int rowbase, int s, int lane) {
  return *(const v8s*)&lds[(rowbase + (lane & 15)) * 64 + s * 32 + ((lane >> 4) << 3)];
}

// ---------- kernel 1: convert/pack weights + labels to bf16 ----------
// regions: wcomb(6144x1024: Wh|Wm|Wih[:, :1024]) whh(4096x1024) wfc(1152x1024, pad0)
//          wlab(4096x64 = Wih[:,1033:1097]) lab(16*256 x 64, row r=t*256+b)
__global__ __launch_bounds__(256) void k_convert(
    const float* __restrict__ Wh, const float* __restrict__ Wm,
    const float* __restrict__ Wih, const float* __restrict__ Whh,
    const float* __restrict__ Wfc, const float* __restrict__ label,
    u16* __restrict__ wcomb, u16* __restrict__ whhb, u16* __restrict__ wfcb,
    u16* __restrict__ wlabb, u16* __restrict__ labb) {
  const int64_t N1 = 6144 * 1024, N2 = 4096 * 1024, N3 = 1152 * 1024, N4 = 4096 * 64;
  int64_t idx = (int64_t)blockIdx.x * 256 + threadIdx.x;
  if (idx < N1) {
    int r = (int)(idx >> 10), c = (int)(idx & 1023);
    float v;
    if (r < 1024) v = Wh[idx];
    else if (r < 2048) v = Wm[(int64_t)(r - 1024) * 1024 + c];
    else v = Wih[(int64_t)(r - 2048) * 1097 + c];
    wcomb[idx] = f2bf(v);
  } else if (idx < N1 + N2) {
    int64_t i2 = idx - N1;
    whhb[i2] = f2bf(Whh[i2]);
  } else if (idx < N1 + N2 + N3) {
    int64_t i2 = idx - (N1 + N2);
    int r = (int)(i2 >> 10), c = (int)(i2 & 1023);
    wfcb[i2] = f2bf(r < 1090 ? Wfc[(int64_t)r * 1024 + c] : 0.f);
  } else if (idx < N1 + N2 + N3 + N4) {
    int64_t i2 = idx - (N1 + N2 + N3);
    int r = (int)(i2 >> 6), l = (int)(i2 & 63);
    wlabb[i2] = f2bf(Wih[(int64_t)r * 1097 + 1033 + l]);
  } else {
    int64_t i2 = idx - (N1 + N2 + N3 + N4);
    int r = (int)(i2 >> 6), l = (int)(i2 & 63);
    int t = r >> 8, b = r & 255;
    labb[i2] = f2bf(label[((int64_t)b * 17 + t) * 64 + l]);
  }
}

// ---------- kernel 2: mean over S ----------
__global__ __launch_bounds__(256) void k_mean(const float* __restrict__ image,
                                              u16* __restrict__ meanbf) {
  int gid = blockIdx.x * 256 + threadIdx.x;  // 65536 threads, 4 elems each
  int b = gid >> 8, ev = gid & 255;
  const float4* src = (const float4*)image + (size_t)b * 65536 + ev;
  float4 s = make_float4(0.f, 0.f, 0.f, 0.f);
#pragma unroll 4
  for (int ss = 0; ss < 256; ++ss) {
    float4 v = src[(size_t)ss * 256];
    s.x += v.x; s.y += v.y; s.z += v.z; s.w += v.w;
  }
  const float inv = 1.f / 256.f;
  ushort4 o;
  o.x = f2bf(s.x * inv); o.y = f2bf(s.y * inv);
  o.z = f2bf(s.z * inv); o.w = f2bf(s.w * inv);
  *(ushort4*)&meanbf[(size_t)b * 1024 + ev * 4] = o;
}

// ---------- kernel 3: packed GEMM mean @ [Wh|Wm|Wih_E]^T -> h0(bf16), m0(f32), base(f32) ----------
__global__ __launch_bounds__(256) void k_gemm_init(
    const u16* __restrict__ meanbf, const u16* __restrict__ wcomb,
    const float* __restrict__ bh, const float* __restrict__ bm,
    const float* __restrict__ bih, const float* __restrict__ bhh,
    const float* __restrict__ vp, const float* __restrict__ Wih,
    u16* __restrict__ hbuf, float* __restrict__ mbuf, float* __restrict__ basebuf) {
  __shared__ alignas(16) u16 lA[64 * 64];
  __shared__ alignas(16) u16 lB[64 * 64];
  const int tid = threadIdx.x, lane = tid & 63, wid = tid >> 6;
  const int bm0 = (blockIdx.x & 3) * 64;
  const int bn0 = (blockIdx.x >> 2) * 64;  // grid = 4*96
  const int wr = wid >> 1, wc = wid & 1;
  v4f acc[2][2];
#pragma unroll
  for (int i = 0; i < 2; ++i)
#pragma unroll
    for (int j = 0; j < 2; ++j) acc[i][j] = (v4f){0.f, 0.f, 0.f, 0.f};

  for (int kt = 0; kt < 16; ++kt) {
    const int k0 = kt * 64;
    stage64(meanbf, 1024, bm0, k0, lA, wid, lane);
    stage64(wcomb, 1024, bn0, k0, lB, wid, lane);
    __syncthreads();
#pragma unroll
    for (int s = 0; s < 2; ++s) {
      v8s a0 = fragAB(lA, wr * 32, s, lane);
      v8s a1 = fragAB(lA, wr * 32 + 16, s, lane);
      v8s b0 = fragAB(lB, wc * 32, s, lane);
      v8s b1 = fragAB(lB, wc * 32 + 16, s, lane);
      acc[0][0] = mfma16(a0, b0, acc[0][0]);
      acc[0][1] = mfma16(a0, b1, acc[0][1]);
      acc[1][0] = mfma16(a1, b0, acc[1][0]);
      acc[1][1] = mfma16(a1, b1, acc[1][1]);
    }
    __syncthreads();
  }
#pragma unroll
  for (int fm = 0; fm < 2; ++fm)
#pragma unroll
    for (int fn = 0; fn < 2; ++fn)
#pragma unroll
      for (int rg = 0; rg < 4; ++rg) {
        int row = bm0 + wr * 32 + fm * 16 + ((lane >> 4) << 2) + rg;  // b
        int col = bn0 + wc * 32 + fn * 16 + (lane & 15);              // packed n
        float v = acc[fm][fn][rg];
        if (col < 1024) {
          hbuf[(size_t)row * 1024 + col] = f2bf(tanhf(v + bh[col]));
        } else if (col < 2048) {
          int nn = col - 1024;
          mbuf[(size_t)row * 1024 + nn] = tanhf(v + bm[nn]);
        } else {
          int j = col - 2048;
          float sv = v + bih[j] + bhh[j];
#pragma unroll
          for (int q = 0; q < 8; ++q)
            sv += vp[row * 8 + q] * Wih[(size_t)j * 1097 + 1024 + q];
          basebuf[(size_t)row * 4096 + j] = sv;
        }
      }
}

// ---------- kernel 4: basefull[t,b,j] = base[b,j] + lab[t,b]@Wlab^T + (t==0)*W_begin[j] ----------
__global__ __launch_bounds__(256) void k_basefull(
    const u16* __restrict__ labb, const u16* __restrict__ wlabb,
    const float* __restrict__ basebuf, const float* __restrict__ Wih,
    u16* __restrict__ bfull) {
  __shared__ alignas(16) u16 lA[64 * 64];
  __shared__ alignas(16) u16 lB[64 * 64];
  const int tid = threadIdx.x, lane = tid & 63, wid = tid >> 6;
  const int bm0 = (blockIdx.x & 63) * 64;   // r = t*256+b
  const int bn0 = (blockIdx.x >> 6) * 64;   // j; grid = 64*64
  const int wr = wid >> 1, wc = wid & 1;
  v4f acc[2][2];
#pragma unroll
  for (int i = 0; i < 2; ++i)
#pragma unroll
    for (int j = 0; j < 2; ++j) acc[i][j] = (v4f){0.f, 0.f, 0.f, 0.f};

  stage64(labb, 64, bm0, 0, lA, wid, lane);
  stage64(wlabb, 64, bn0, 0, lB, wid, lane);
  __syncthreads();
#pragma unroll
  for (int s = 0; s < 2; ++s) {
    v8s a0 = fragAB(lA, wr * 32, s, lane);
    v8s a1 = fragAB(lA, wr * 32 + 16, s, lane);
    v8s b0 = fragAB(lB, wc * 32, s, lane);
    v8s b1 = fragAB(lB, wc * 32 + 16, s, lane);
    acc[0][0] = mfma16(a0, b0, acc[0][0]);
    acc[0][1] = mfma16(a0, b1, acc[0][1]);
    acc[1][0] = mfma16(a1, b0, acc[1][0]);
    acc[1][1] = mfma16(a1, b1, acc[1][1]);
  }
#pragma unroll
  for (int fm = 0; fm < 2; ++fm)
#pragma unroll
    for (int fn = 0; fn < 2; ++fn)
#pragma unroll
      for (int rg = 0; rg < 4; ++rg) {
        int r = bm0 + wr * 32 + fm * 16 + ((lane >> 4) << 2) + rg;
        int j = bn0 + wc * 32 + fn * 16 + (lane & 15);
        int t = r >> 8, b = r & 255;
        float v = acc[fm][fn][rg] + basebuf[(size_t)b * 4096 + j];
        if (t == 0) v += Wih[(size_t)j * 1097 + 1032];
        bfull[(size_t)r * 4096 + j] = f2bf(v);
      }
}

// ---------- kernel 5: one LSTM step (fused 4-gate GEMM + activations) ----------
__global__ __launch_bounds__(256) void k_step(
    const u16* __restrict__ hprev, const u16* __restrict__ whhb,
    const u16* __restrict__ bft, float* __restrict__ mbuf,
    u16* __restrict__ hnext) {
  __shared__ alignas(16) u16 lA[32 * 64];
  __shared__ alignas(16) u16 lB[4][32 * 64];
  __shared__ alignas(16) float lact[4][32 * 32];
  const int tid = threadIdx.x, lane = tid & 63, wid = tid >> 6;
  const int b0 = (blockIdx.x & 7) * 32;
  const int n0 = (blockIdx.x >> 3) * 32;  // grid 8*32 = 256
  v4f acc[2][2];
#pragma unroll
  for (int i = 0; i < 2; ++i)
#pragma unroll
    for (int j = 0; j < 2; ++j) acc[i][j] = (v4f){0.f, 0.f, 0.f, 0.f};

  for (int kt = 0; kt < 16; ++kt) {
    const int k0 = kt * 64;
    {  // A chunk: wave wid stages 8 rows of h tile
      int r = wid * 8 + (lane >> 3);
      int cs = (lane & 7) * 8;
      gll16(hprev + (size_t)(b0 + r) * 1024 + k0 + cs, lA + wid * 8 * 64);
    }
#pragma unroll
    for (int c = 0; c < 4; ++c) {  // B: wave wid stages its gate's 32 rows
      int r = c * 8 + (lane >> 3);
      int cs = (lane & 7) * 8;
      gll16(whhb + (size_t)(wid * 1024 + n0 + r) * 1024 + k0 + cs, &lB[wid][c * 8 * 64]);
    }
    __syncthreads();
#pragma unroll
    for (int s = 0; s < 2; ++s) {
      v8s a0 = fragAB(lA, 0, s, lane);
      v8s a1 = fragAB(lA, 16, s, lane);
      v8s b0 = fragAB(lB[wid], 0, s, lane);
      v8s b1 = fragAB(lB[wid], 16, s, lane);
      acc[0][0] = mfma16(a0, b0, acc[0][0]);
      acc[0][1] = mfma16(a0, b1, acc[0][1]);
      acc[1][0] = mfma16(a1, b0, acc[1][0]);
      acc[1][1] = mfma16(a1, b1, acc[1][1]);
    }
    __syncthreads();
  }
#pragma unroll
  for (int fm = 0; fm < 2; ++fm)
#pragma unroll
    for (int fn = 0; fn < 2; ++fn)
#pragma unroll
      for (int rg = 0; rg < 4; ++rg) {
        int rr = fm * 16 + ((lane >> 4) << 2) + rg;
        int cc = fn * 16 + (lane & 15);
        lact[wid][rr * 32 + cc] = acc[fm][fn][rg];
      }
  __syncthreads();
  // phase 2: activations, 4 consecutive n per thread
  const int rowm = tid >> 3;
  const int nql = (tid & 7) * 4;
  const int b = b0 + rowm;
  const int n = n0 + nql;
  const u16* bb = bft + (size_t)b * 4096 + n;
  ushort4 ui = *(const ushort4*)(bb);
  ushort4 uf = *(const ushort4*)(bb + 1024);
  ushort4 ug = *(const ushort4*)(bb + 2048);
  ushort4 uo = *(const ushort4*)(bb + 3072);
  float4 mo = *(const float4*)&mbuf[(size_t)b * 1024 + n];
  float m2a[4];
  u16 h2a[4];
#pragma unroll
  for (int q = 0; q < 4; ++q) {
    float gi = lact[0][rowm * 32 + nql + q] + bf2f(((const u16*)&ui)[q]);
    float gf = lact[1][rowm * 32 + nql + q] + bf2f(((const u16*)&uf)[q]);
    float gg = lact[2][rowm * 32 + nql + q] + bf2f(((const u16*)&ug)[q]);
    float go = lact[3][rowm * 32 + nql + q] + bf2f(((const u16*)&uo)[q]);
    float mov = ((const float*)&mo)[q];
    float m2 = sigf(gf) * mov + sigf(gi) * tanhf(gg);
    float h2 = sigf(go) * tanhf(m2);
    m2a[q] = m2;
    h2a[q] = f2bf(h2);
  }
  *(float4*)&mbuf[(size_t)b * 1024 + n] = make_float4(m2a[0], m2a[1], m2a[2], m2a[3]);
  ushort4 ho;
  ho.x = h2a[0]; ho.y = h2a[1]; ho.z = h2a[2]; ho.w = h2a[3];
  *(ushort4*)&hnext[(size_t)b * 1024 + n] = ho;
}

// ---------- kernel 6: batched FC + epilogue + mask ----------
__global__ __launch_bounds__(256) void k_fc(
    const u16* __restrict__ hall, const u16* __restrict__ wfcb,
    const float* __restrict__ bfc, const int* __restrict__ length,
    float* __restrict__ out) {
  __shared__ alignas(16) u16 lA[64 * 64];
  __shared__ alignas(16) u16 lB[64 * 64];
  const int tid = threadIdx.x, lane = tid & 63, wid = tid >> 6;
  const int bm0 = (int)(blockIdx.x % 64) * 64;  // r = t*256+b (M=4096)
  const int bn0 = (int)(blockIdx.x / 64) * 64;  // j (N=1152); grid 64*18
  const int wr = wid >> 1, wc = wid & 1;
  v4f acc[2][2];
#pragma unroll
  for (int i = 0; i < 2; ++i)
#pragma unroll
    for (int j = 0; j < 2; ++j) acc[i][j] = (v4f){0.f, 0.f, 0.f, 0.f};

  for (int kt = 0; kt < 16; ++kt) {
    const int k0 = kt * 64;
    stage64(hall, 1024, bm0, k0, lA, wid, lane);
    stage64(wfcb, 1024, bn0, k0, lB, wid, lane);
    __syncthreads();
#pragma unroll
    for (int s = 0; s < 2; ++s) {
      v8s a0 = fragAB(lA, wr * 32, s, lane);
      v8s a1 = fragAB(lA, wr * 32 + 16, s, lane);
      v8s b0 = fragAB(lB, wc * 32, s, lane);
      v8s b1 = fragAB(lB, wc * 32 + 16, s, lane);
      acc[0][0] = mfma16(a0, b0, acc[0][0]);
      acc[0][1] = mfma16(a0, b1, acc[0][1]);
      acc[1][0] = mfma16(a1, b0, acc[1][0]);
      acc[1][1] = mfma16(a1, b1, acc[1][1]);
    }
    __syncthreads();
  }
#pragma unroll
  for (int fm = 0; fm < 2; ++fm)
#pragma unroll
    for (int fn = 0; fn < 2; ++fn)
#pragma unroll
      for (int rg = 0; rg < 4; ++rg) {
        int r = bm0 + wr * 32 + fm * 16 + ((lane >> 4) << 2) + rg;
        int j = bn0 + wc * 32 + fn * 16 + (lane & 15);
        if (j < 64 || j >= 1090) continue;
        int t = r >> 8, b = r & 255;
        float v = acc[fm][fn][rg] + bfc[j];
        int c;
        if (j < 1088) { c = j - 64; v = fmaxf(v, 0.f); }          // topic: relu
        else if (j == 1088) { c = 1024; v = 1.f / (1.f + expf(-v)); }  // stop
        else { c = 1025; v = expf(v); }                            // temp
        if (t >= length[b] - 1) v = 0.f;                           // pad mask
        out[((size_t)t * 256 + b) * 1026 + c] = v;
      }
}

extern "C" void kernel_launch(void* const* d_in, const int* in_sizes, int n_in,
                              void* d_out, int out_size, void* d_ws, size_t ws_size,
                              hipStream_t stream) {
  (void)in_sizes; (void)n_in; (void)out_size; (void)ws_size;
  const float* image  = (const float*)d_in[0];
  const float* vp     = (const float*)d_in[1];
  const float* label  = (const float*)d_in[2];
  const int*   length = (const int*)d_in[3];
  const float* Wh  = (const float*)d_in[4];
  const float* bh  = (const float*)d_in[5];
  const float* Wm  = (const float*)d_in[6];
  const float* bm  = (const float*)d_in[7];
  const float* Wih = (const float*)d_in[8];
  const float* Whh = (const float*)d_in[9];
  const float* bih = (const float*)d_in[10];
  const float* bhh = (const float*)d_in[11];
  const float* Wfc = (const float*)d_in[12];
  const float* bfc = (const float*)d_in[13];
  float* out = (float*)d_out;
  char* ws = (char*)d_ws;

  size_t off = 0;
  u16* wcomb  = (u16*)(ws + off); off += (size_t)6144 * 1024 * 2;
  u16* whhb   = (u16*)(ws + off); off += (size_t)4096 * 1024 * 2;
  u16* wfcb   = (u16*)(ws + off); off += (size_t)1152 * 1024 * 2;
  u16* wlabb  = (u16*)(ws + off); off += (size_t)4096 * 64 * 2;
  u16* labb   = (u16*)(ws + off); off += (size_t)4096 * 64 * 2;
  u16* meanbf = (u16*)(ws + off); off += (size_t)256 * 1024 * 2;
  u16* hbuf   = (u16*)(ws + off); off += (size_t)17 * 256 * 1024 * 2;
  float* mbuf    = (float*)(ws + off); off += (size_t)256 * 1024 * 4;
  float* basebuf = (float*)(ws + off); off += (size_t)256 * 4096 * 4;
  u16* bfull  = (u16*)(ws + off); off += (size_t)16 * 256 * 4096 * 2;
  // total ~72.6 MB of d_ws

  k_convert<<<47616, 256, 0, stream>>>(Wh, Wm, Wih, Whh, Wfc, label,
                                       wcomb, whhb, wfcb, wlabb, labb);
  k_mean<<<256, 256, 0, stream>>>(image, meanbf);
  k_gemm_init<<<384, 256, 0, stream>>>(meanbf, wcomb, bh, bm, bih, bhh, vp, Wih,
                                       hbuf, mbuf, basebuf);
  k_basefull<<<4096, 256, 0, stream>>>(labb, wlabb, basebuf, Wih, bfull);
  for (int t = 0; t < 16; ++t) {
    k_step<<<256, 256, 0, stream>>>(hbuf + (size_t)t * 256 * 1024, whhb,
                                    bfull + (size_t)t * 256 * 4096, mbuf,
                                    hbuf + (size_t)(t + 1) * 256 * 1024);
  }
  k_fc<<<1152, 256, 0, stream>>>(hbuf + (size_t)256 * 1024, wfcb, bfc, length, out);
}

// Round 2
// 347.822 us; speedup vs baseline: 1.2063x; 1.2063x over previous
//
#include <hip/hip_runtime.h>
#include <stdint.h>

typedef unsigned short u16;
typedef __attribute__((ext_vector_type(8))) short v8s;
typedef __attribute__((ext_vector_type(4))) float v4f;

// ---------- helpers ----------
__device__ __forceinline__ u16 f2bf(float f) {
  uint32_t x = __float_as_uint(f);
  return (u16)((x + 0x7fffu + ((x >> 16) & 1u)) >> 16);
}
__device__ __forceinline__ float bf2f(u16 u) {
  return __uint_as_float(((uint32_t)u) << 16);
}
__device__ __forceinline__ float sigf(float x) { return 1.f / (1.f + __expf(-x)); }

__device__ __forceinline__ v4f mfma16(v8s a, v8s b, v4f c) {
  return __builtin_amdgcn_mfma_f32_16x16x32_bf16(a, b, c, 0, 0, 0);
}

// async global->LDS, 16B/lane; LDS dest wave-uniform (HW adds lane*16)
__device__ __forceinline__ void gll16(const u16* src, u16* ldsdst) {
  __builtin_amdgcn_global_load_lds(
      reinterpret_cast<__attribute__((address_space(1))) uint32_t*>(
          reinterpret_cast<uintptr_t>(src)),
      reinterpret_cast<__attribute__((address_space(3))) uint32_t*>(
          reinterpret_cast<uintptr_t>(ldsdst)),
      16, 0, 0);
}

// Fragment-packed (FP) layout for bf16 matrix M[R][K] (R%16==0, K%64==0, KT=K/64):
// 16-bit elem offset fpoff(row,k) =
//   ((( (row>>4)*KT + (k>>6) )*2 + ((k>>5)&1))*64 + ((k>>3)&3)*16 + (row&15))*8 + (k&7)
// A 16x64 tile = 1024 u16 (two 512-u16 chunks s=0,1); chunk s, lane l (= q*16+r)
// holds M[tr*16+r][tk*64 + s*32 + q*8 .. +7]. Staging a chunk = one wave-uniform
// gll16; fragment read for (s) = v8s at tile*1024 + s*512 + lane*8 (conflict-free).
__device__ __forceinline__ size_t fpoff(int row, int k, int KT) {
  return ((size_t)(((row >> 4) * KT + (k >> 6)) * 2 + ((k >> 5) & 1)) * 64 +
          ((k >> 3) & 3) * 16 + (row & 15)) * 8 + (k & 7);
}

__device__ __forceinline__ void load8(const float* p, float* f) {
  float4 a = *(const float4*)p;
  float4 b = *(const float4*)(p + 4);
  f[0]=a.x; f[1]=a.y; f[2]=a.z; f[3]=a.w; f[4]=b.x; f[5]=b.y; f[6]=b.z; f[7]=b.w;
}
__device__ __forceinline__ void store8bf(u16* dst, const float* f) {
  u16 t[8];
#pragma unroll
  for (int i = 0; i < 8; ++i) t[i] = f2bf(f[i]);
  *(v8s*)dst = *(const v8s*)t;
}

// ---------- kernel 1: convert/pack all GEMM operands to FP-bf16 ----------
// wcomb (6144x1024: Wh|Wm|Wih[:,:1024]), whhb (4096x1024), wfcb (1152x1024 pad0),
// wlabb (4096x64 = Wih[:,1033:1097]), labb (4096x64, row r=t*256+b).
__global__ __launch_bounds__(256) void k_convert(
    const float* __restrict__ Wh, const float* __restrict__ Wm,
    const float* __restrict__ Wih, const float* __restrict__ Whh,
    const float* __restrict__ Wfc, const float* __restrict__ label,
    u16* __restrict__ wcomb, u16* __restrict__ whhb, u16* __restrict__ wfcb,
    u16* __restrict__ wlabb, u16* __restrict__ labb) {
  // unit = one 16B FP block (8 u16). counts: 786432,524288,147456,32768,32768
  int64_t u = (int64_t)blockIdx.x * 256 + threadIdx.x;
  float f[8];
  if (u < 786432) {  // wcomb, KT=16
    int lu = (int)u;
    int r15 = lu & 15, q = (lu >> 4) & 3, s = (lu >> 6) & 1, tile = lu >> 7;
    int tk = tile & 15, tr = tile >> 4;
    int row = tr * 16 + r15, k = tk * 64 + s * 32 + q * 8;
    if (row < 1024) load8(Wh + (size_t)row * 1024 + k, f);
    else if (row < 2048) load8(Wm + (size_t)(row - 1024) * 1024 + k, f);
    else {
      const float* p = Wih + (size_t)(row - 2048) * 1097 + k;
#pragma unroll
      for (int i = 0; i < 8; ++i) f[i] = p[i];
    }
    store8bf(wcomb + (size_t)lu * 8, f);
  } else if (u < 1310720) {  // whhb, KT=16
    int lu = (int)(u - 786432);
    int r15 = lu & 15, q = (lu >> 4) & 3, s = (lu >> 6) & 1, tile = lu >> 7;
    int tk = tile & 15, tr = tile >> 4;
    int row = tr * 16 + r15, k = tk * 64 + s * 32 + q * 8;
    load8(Whh + (size_t)row * 1024 + k, f);
    store8bf(whhb + (size_t)lu * 8, f);
  } else if (u < 1458176) {  // wfcb, KT=16, rows>=1090 zero
    int lu = (int)(u - 1310720);
    int r15 = lu & 15, q = (lu >> 4) & 3, s = (lu >> 6) & 1, tile = lu >> 7;
    int tk = tile & 15, tr = tile >> 4;
    int row = tr * 16 + r15, k = tk * 64 + s * 32 + q * 8;
    if (row < 1090) load8(Wfc + (size_t)row * 1024 + k, f);
    else {
#pragma unroll
      for (int i = 0; i < 8; ++i) f[i] = 0.f;
    }
    store8bf(wfcb + (size_t)lu * 8, f);
  } else if (u < 1490944) {  // wlabb, KT=1
    int lu = (int)(u - 1458176);
    int r15 = lu & 15, q = (lu >> 4) & 3, s = (lu >> 6) & 1, tile = lu >> 7;
    int row = tile * 16 + r15, k = s * 32 + q * 8;
    const float* p = Wih + (size_t)row * 1097 + 1033 + k;
#pragma unroll
    for (int i = 0; i < 8; ++i) f[i] = p[i];
    store8bf(wlabb + (size_t)lu * 8, f);
  } else {  // labb, KT=1, row=t*256+b
    int lu = (int)(u - 1490944);
    int r15 = lu & 15, q = (lu >> 4) & 3, s = (lu >> 6) & 1, tile = lu >> 7;
    int row = tile * 16 + r15, k = s * 32 + q * 8;
    int t = row >> 8, b = row & 255;
    load8(label + ((size_t)b * 17 + t) * 64 + k, f);
    store8bf(labb + (size_t)lu * 8, f);
  }
}

// ---------- kernel 2a/2b: mean over S (two passes for memory parallelism) ----------
__global__ __launch_bounds__(256) void k_mean1(const float* __restrict__ image,
                                               float4* __restrict__ pacc) {
  int bi = blockIdx.x;  // 1024 = b(256) x qtr(4)
  int b = bi >> 2, qtr = bi & 3, tid = threadIdx.x;
  const float4* src = (const float4*)image + (size_t)b * 65536 + (size_t)qtr * 64 * 256 + tid;
  float4 s = make_float4(0.f, 0.f, 0.f, 0.f);
#pragma unroll 8
  for (int ss = 0; ss < 64; ++ss) {
    float4 v = src[(size_t)ss * 256];
    s.x += v.x; s.y += v.y; s.z += v.z; s.w += v.w;
  }
  pacc[(size_t)bi * 256 + tid] = s;
}
__global__ __launch_bounds__(256) void k_mean2(const float4* __restrict__ pacc,
                                               u16* __restrict__ meanbf) {
  int b = blockIdx.x, tid = threadIdx.x;
  float4 s = make_float4(0.f, 0.f, 0.f, 0.f);
#pragma unroll
  for (int q = 0; q < 4; ++q) {
    float4 v = pacc[((size_t)b * 4 + q) * 256 + tid];
    s.x += v.x; s.y += v.y; s.z += v.z; s.w += v.w;
  }
  const float inv = 1.f / 256.f;
  int k = tid * 4;
  ushort4 o;
  o.x = f2bf(s.x * inv); o.y = f2bf(s.y * inv);
  o.z = f2bf(s.z * inv); o.w = f2bf(s.w * inv);
  *(ushort4*)&meanbf[fpoff(b, k, 16)] = o;  // k%4==0, k&7 in {0,4}: 8B aligned
}

// ---------- kernel 3: mean @ [Wh|Wm|Wih_E]^T -> h0(FP bf16), m0(f32), base(f32) ----------
__global__ __launch_bounds__(256) void k_gemm_init(
    const u16* __restrict__ meanbf, const u16* __restrict__ wcomb,
    const float* __restrict__ bh, const float* __restrict__ bm,
    const float* __restrict__ bih, const float* __restrict__ bhh,
    const float* __restrict__ vp, const float* __restrict__ Wih,
    u16* __restrict__ hbuf, float* __restrict__ mbuf, float* __restrict__ basebuf) {
  __shared__ alignas(16) u16 lA[4 * 1024];
  __shared__ alignas(16) u16 lB[4 * 1024];
  const int tid = threadIdx.x, lane = tid & 63, wid = tid >> 6;
  const int bm0 = (blockIdx.x & 3) * 64;
  const int bn0 = (blockIdx.x >> 2) * 64;  // grid 4*96
  const int wr = wid >> 1, wc = wid & 1;
  v4f acc[2][2];
#pragma unroll
  for (int i = 0; i < 2; ++i)
#pragma unroll
    for (int j = 0; j < 2; ++j) acc[i][j] = (v4f){0.f, 0.f, 0.f, 0.f};

  for (int kt = 0; kt < 16; ++kt) {
    const u16* asrc = meanbf + ((size_t)((bm0 >> 4) + wid) * 16 + kt) * 1024 + lane * 8;
    gll16(asrc, lA + wid * 1024);
    gll16(asrc + 512, lA + wid * 1024 + 512);
    const u16* bsrc = wcomb + ((size_t)((bn0 >> 4) + wid) * 16 + kt) * 1024 + lane * 8;
    gll16(bsrc, lB + wid * 1024);
    gll16(bsrc + 512, lB + wid * 1024 + 512);
    __syncthreads();
#pragma unroll
    for (int s = 0; s < 2; ++s) {
      v8s a0 = *(const v8s*)&lA[(size_t)(wr * 2) * 1024 + s * 512 + lane * 8];
      v8s a1 = *(const v8s*)&lA[(size_t)(wr * 2 + 1) * 1024 + s * 512 + lane * 8];
      v8s b0 = *(const v8s*)&lB[(size_t)(wc * 2) * 1024 + s * 512 + lane * 8];
      v8s b1 = *(const v8s*)&lB[(size_t)(wc * 2 + 1) * 1024 + s * 512 + lane * 8];
      acc[0][0] = mfma16(a0, b0, acc[0][0]);
      acc[0][1] = mfma16(a0, b1, acc[0][1]);
      acc[1][0] = mfma16(a1, b0, acc[1][0]);
      acc[1][1] = mfma16(a1, b1, acc[1][1]);
    }
    __syncthreads();
  }
#pragma unroll
  for (int fm = 0; fm < 2; ++fm)
#pragma unroll
    for (int fn = 0; fn < 2; ++fn)
#pragma unroll
      for (int rg = 0; rg < 4; ++rg) {
        int row = bm0 + wr * 32 + fm * 16 + ((lane >> 4) << 2) + rg;  // b
        int col = bn0 + wc * 32 + fn * 16 + (lane & 15);              // packed n
        float v = acc[fm][fn][rg];
        if (col < 1024) {
          hbuf[fpoff(row, col, 16)] = f2bf(tanhf(v + bh[col]));
        } else if (col < 2048) {
          int nn = col - 1024;
          mbuf[(size_t)row * 1024 + nn] = tanhf(v + bm[nn]);
        } else {
          int j = col - 2048;
          float sv = v + bih[j] + bhh[j];
#pragma unroll
          for (int q = 0; q < 8; ++q)
            sv += vp[row * 8 + q] * Wih[(size_t)j * 1097 + 1024 + q];
          basebuf[(size_t)row * 4096 + j] = sv;
        }
      }
}

// ---------- kernel 4: bfull[t,b,j] = base[b,j] + lab@Wlab^T + (t==0)*W_begin ----------
__global__ __launch_bounds__(256) void k_basefull(
    const u16* __restrict__ labb, const u16* __restrict__ wlabb,
    const float* __restrict__ basebuf, const float* __restrict__ Wih,
    u16* __restrict__ bfull) {
  __shared__ alignas(16) u16 lA[4 * 1024];
  __shared__ alignas(16) u16 lB[4 * 1024];
  const int tid = threadIdx.x, lane = tid & 63, wid = tid >> 6;
  const int bm0 = (blockIdx.x & 63) * 64;   // r = t*256+b
  const int bn0 = (blockIdx.x >> 6) * 64;   // j; grid 64*64
  const int wr = wid >> 1, wc = wid & 1;
  v4f acc[2][2];
#pragma unroll
  for (int i = 0; i < 2; ++i)
#pragma unroll
    for (int j = 0; j < 2; ++j) acc[i][j] = (v4f){0.f, 0.f, 0.f, 0.f};

  // KT=1: single k-tile
  const u16* asrc = labb + (size_t)((bm0 >> 4) + wid) * 1024 + lane * 8;
  gll16(asrc, lA + wid * 1024);
  gll16(asrc + 512, lA + wid * 1024 + 512);
  const u16* bsrc = wlabb + (size_t)((bn0 >> 4) + wid) * 1024 + lane * 8;
  gll16(bsrc, lB + wid * 1024);
  gll16(bsrc + 512, lB + wid * 1024 + 512);
  __syncthreads();
#pragma unroll
  for (int s = 0; s < 2; ++s) {
    v8s a0 = *(const v8s*)&lA[(size_t)(wr * 2) * 1024 + s * 512 + lane * 8];
    v8s a1 = *(const v8s*)&lA[(size_t)(wr * 2 + 1) * 1024 + s * 512 + lane * 8];
    v8s b0 = *(const v8s*)&lB[(size_t)(wc * 2) * 1024 + s * 512 + lane * 8];
    v8s b1 = *(const v8s*)&lB[(size_t)(wc * 2 + 1) * 1024 + s * 512 + lane * 8];
    acc[0][0] = mfma16(a0, b0, acc[0][0]);
    acc[0][1] = mfma16(a0, b1, acc[0][1]);
    acc[1][0] = mfma16(a1, b0, acc[1][0]);
    acc[1][1] = mfma16(a1, b1, acc[1][1]);
  }
#pragma unroll
  for (int fm = 0; fm < 2; ++fm)
#pragma unroll
    for (int fn = 0; fn < 2; ++fn)
#pragma unroll
      for (int rg = 0; rg < 4; ++rg) {
        int r = bm0 + wr * 32 + fm * 16 + ((lane >> 4) << 2) + rg;
        int j = bn0 + wc * 32 + fn * 16 + (lane & 15);
        int t = r >> 8, b = r & 255;
        float v = acc[fm][fn][rg] + basebuf[(size_t)b * 4096 + j];
        if (t == 0) v += Wih[(size_t)j * 1097 + 1032];
        bfull[(size_t)r * 4096 + j] = f2bf(v);
      }
}

// ---------- kernel 5: one LSTM step (double-buffered fused 4-gate GEMM) ----------
__global__ __launch_bounds__(256) void k_step(
    const u16* __restrict__ hprev, const u16* __restrict__ whhb,
    const u16* __restrict__ bft, float* __restrict__ mbuf,
    u16* __restrict__ hnext) {
  __shared__ alignas(16) u16 lA[2][2 * 1024];
  __shared__ alignas(16) u16 lB[2][8 * 1024];
  __shared__ alignas(16) float lact[4][32 * 33];
  const int tid = threadIdx.x, lane = tid & 63, wid = tid >> 6;
  const int b0 = (blockIdx.x & 7) * 32;
  const int n0 = (blockIdx.x >> 3) * 32;  // grid 8*32 = 256
  const int atr = b0 >> 4;                 // A tiles atr, atr+1 (KT=16)
  v4f acc[2][2];
#pragma unroll
  for (int i = 0; i < 2; ++i)
#pragma unroll
    for (int j = 0; j < 2; ++j) acc[i][j] = (v4f){0.f, 0.f, 0.f, 0.f};

  // per-wave staging: A chunk (tile wid>>1, s=wid&1); B tiles 2*wid,2*wid+1 (gate wid)
  auto stage = [&](int kt, int buf) {
    gll16(hprev + ((size_t)(atr + (wid >> 1)) * 16 + kt) * 1024 + (wid & 1) * 512 + lane * 8,
          &lA[buf][(wid >> 1) * 1024 + (wid & 1) * 512]);
#pragma unroll
    for (int jj = 0; jj < 2; ++jj) {
      int j = 2 * wid + jj;                       // local B tile
      int tr = wid * 64 + (n0 >> 4) + jj;         // gate wid rows
      const u16* bsrc = whhb + ((size_t)tr * 16 + kt) * 1024 + lane * 8;
      gll16(bsrc, &lB[buf][j * 1024]);
      gll16(bsrc + 512, &lB[buf][j * 1024 + 512]);
    }
  };

  stage(0, 0);
  __syncthreads();
  for (int kt = 0; kt < 16; ++kt) {
    const int cur = kt & 1;
    if (kt < 15) stage(kt + 1, cur ^ 1);
#pragma unroll
    for (int s = 0; s < 2; ++s) {
      v8s a0 = *(const v8s*)&lA[cur][s * 512 + lane * 8];
      v8s a1 = *(const v8s*)&lA[cur][1024 + s * 512 + lane * 8];
      v8s b0 = *(const v8s*)&lB[cur][(size_t)(2 * wid) * 1024 + s * 512 + lane * 8];
      v8s b1 = *(const v8s*)&lB[cur][(size_t)(2 * wid + 1) * 1024 + s * 512 + lane * 8];
      acc[0][0] = mfma16(a0, b0, acc[0][0]);
      acc[0][1] = mfma16(a0, b1, acc[0][1]);
      acc[1][0] = mfma16(a1, b0, acc[1][0]);
      acc[1][1] = mfma16(a1, b1, acc[1][1]);
    }
    __syncthreads();  // drains vmcnt+lgkmcnt: next-kt staging complete, reads done
  }
#pragma unroll
  for (int fm = 0; fm < 2; ++fm)
#pragma unroll
    for (int fn = 0; fn < 2; ++fn)
#pragma unroll
      for (int rg = 0; rg < 4; ++rg) {
        int rr = fm * 16 + ((lane >> 4) << 2) + rg;
        int cc = fn * 16 + (lane & 15);
        lact[wid][rr * 33 + cc] = acc[fm][fn][rg];
      }
  __syncthreads();
  // activations: thread -> (b0+rowm, n0+nql..+3)
  const int rowm = tid >> 3;
  const int nql = (tid & 7) * 4;
  const int b = b0 + rowm;
  const int n = n0 + nql;
  const u16* bb = bft + (size_t)b * 4096 + n;
  ushort4 ui = *(const ushort4*)(bb);
  ushort4 uf = *(const ushort4*)(bb + 1024);
  ushort4 ug = *(const ushort4*)(bb + 2048);
  ushort4 uo = *(const ushort4*)(bb + 3072);
  float4 mo = *(const float4*)&mbuf[(size_t)b * 1024 + n];
  float m2a[4];
  u16 h2a[4];
#pragma unroll
  for (int q = 0; q < 4; ++q) {
    float gi = lact[0][rowm * 33 + nql + q] + bf2f(((const u16*)&ui)[q]);
    float gf = lact[1][rowm * 33 + nql + q] + bf2f(((const u16*)&uf)[q]);
    float gg = lact[2][rowm * 33 + nql + q] + bf2f(((const u16*)&ug)[q]);
    float go = lact[3][rowm * 33 + nql + q] + bf2f(((const u16*)&uo)[q]);
    float mov = ((const float*)&mo)[q];
    float m2 = sigf(gf) * mov + sigf(gi) * tanhf(gg);
    float h2 = sigf(go) * tanhf(m2);
    m2a[q] = m2;
    h2a[q] = f2bf(h2);
  }
  *(float4*)&mbuf[(size_t)b * 1024 + n] = make_float4(m2a[0], m2a[1], m2a[2], m2a[3]);
  ushort4 ho;
  ho.x = h2a[0]; ho.y = h2a[1]; ho.z = h2a[2]; ho.w = h2a[3];
  *(ushort4*)&hnext[fpoff(b, n, 16)] = ho;  // n%4==0: 8B-aligned FP write
}

// ---------- kernel 6: batched FC + epilogue + mask ----------
__global__ __launch_bounds__(256) void k_fc(
    const u16* __restrict__ hall, const u16* __restrict__ wfcb,
    const float* __restrict__ bfc, const int* __restrict__ length,
    float* __restrict__ out) {
  __shared__ alignas(16) u16 lA[4 * 1024];
  __shared__ alignas(16) u16 lB[4 * 1024];
  const int tid = threadIdx.x, lane = tid & 63, wid = tid >> 6;
  const int bm0 = (int)(blockIdx.x % 64) * 64;  // r = (t-1)*256+b, M=4096
  const int bn0 = (int)(blockIdx.x / 64) * 64;  // j, N=1152; grid 64*18
  const int wr = wid >> 1, wc = wid & 1;
  v4f acc[2][2];
#pragma unroll
  for (int i = 0; i < 2; ++i)
#pragma unroll
    for (int j = 0; j < 2; ++j) acc[i][j] = (v4f){0.f, 0.f, 0.f, 0.f};

  for (int kt = 0; kt < 16; ++kt) {
    const u16* asrc = hall + ((size_t)((bm0 >> 4) + wid) * 16 + kt) * 1024 + lane * 8;
    gll16(asrc, lA + wid * 1024);
    gll16(asrc + 512, lA + wid * 1024 + 512);
    const u16* bsrc = wfcb + ((size_t)((bn0 >> 4) + wid) * 16 + kt) * 1024 + lane * 8;
    gll16(bsrc, lB + wid * 1024);
    gll16(bsrc + 512, lB + wid * 1024 + 512);
    __syncthreads();
#pragma unroll
    for (int s = 0; s < 2; ++s) {
      v8s a0 = *(const v8s*)&lA[(size_t)(wr * 2) * 1024 + s * 512 + lane * 8];
      v8s a1 = *(const v8s*)&lA[(size_t)(wr * 2 + 1) * 1024 + s * 512 + lane * 8];
      v8s b0 = *(const v8s*)&lB[(size_t)(wc * 2) * 1024 + s * 512 + lane * 8];
      v8s b1 = *(const v8s*)&lB[(size_t)(wc * 2 + 1) * 1024 + s * 512 + lane * 8];
      acc[0][0] = mfma16(a0, b0, acc[0][0]);
      acc[0][1] = mfma16(a0, b1, acc[0][1]);
      acc[1][0] = mfma16(a1, b0, acc[1][0]);
      acc[1][1] = mfma16(a1, b1, acc[1][1]);
    }
    __syncthreads();
  }
#pragma unroll
  for (int fm = 0; fm < 2; ++fm)
#pragma unroll
    for (int fn = 0; fn < 2; ++fn)
#pragma unroll
      for (int rg = 0; rg < 4; ++rg) {
        int r = bm0 + wr * 32 + fm * 16 + ((lane >> 4) << 2) + rg;
        int j = bn0 + wc * 32 + fn * 16 + (lane & 15);
        if (j < 64 || j >= 1090) continue;
        int t = r >> 8, b = r & 255;
        float v = acc[fm][fn][rg] + bfc[j];
        int c;
        if (j < 1088) { c = j - 64; v = fmaxf(v, 0.f); }
        else if (j == 1088) { c = 1024; v = 1.f / (1.f + expf(-v)); }
        else { c = 1025; v = expf(v); }
        if (t >= length[b] - 1) v = 0.f;
        out[((size_t)t * 256 + b) * 1026 + c] = v;
      }
}

extern "C" void kernel_launch(void* const* d_in, const int* in_sizes, int n_in,
                              void* d_out, int out_size, void* d_ws, size_t ws_size,
                              hipStream_t stream) {
  (void)in_sizes; (void)n_in; (void)out_size; (void)ws_size;
  const float* image  = (const float*)d_in[0];
  const float* vp     = (const float*)d_in[1];
  const float* label  = (const float*)d_in[2];
  const int*   length = (const int*)d_in[3];
  const float* Wh  = (const float*)d_in[4];
  const float* bh  = (const float*)d_in[5];
  const float* Wm  = (const float*)d_in[6];
  const float* bm  = (const float*)d_in[7];
  const float* Wih = (const float*)d_in[8];
  const float* Whh = (const float*)d_in[9];
  const float* bih = (const float*)d_in[10];
  const float* bhh = (const float*)d_in[11];
  const float* Wfc = (const float*)d_in[12];
  const float* bfc = (const float*)d_in[13];
  float* out = (float*)d_out;
  char* ws = (char*)d_ws;

  size_t off = 0;
  u16* wcomb  = (u16*)(ws + off); off += (size_t)6144 * 1024 * 2;
  u16* whhb   = (u16*)(ws + off); off += (size_t)4096 * 1024 * 2;
  u16* wfcb   = (u16*)(ws + off); off += (size_t)1152 * 1024 * 2;
  u16* wlabb  = (u16*)(ws + off); off += (size_t)4096 * 64 * 2;
  u16* labb   = (u16*)(ws + off); off += (size_t)4096 * 64 * 2;
  u16* meanbf = (u16*)(ws + off); off += (size_t)256 * 1024 * 2;
  u16* hbuf   = (u16*)(ws + off); off += (size_t)17 * 256 * 1024 * 2;
  float* mbuf    = (float*)(ws + off); off += (size_t)256 * 1024 * 4;
  float* basebuf = (float*)(ws + off); off += (size_t)256 * 4096 * 4;
  u16* bfull  = (u16*)(ws + off); off += (size_t)16 * 256 * 4096 * 2;
  float4* pacc = (float4*)bfull;  // 4 MB scratch, dead before k_basefull writes bfull

  k_convert<<<5952, 256, 0, stream>>>(Wh, Wm, Wih, Whh, Wfc, label,
                                      wcomb, whhb, wfcb, wlabb, labb);
  k_mean1<<<1024, 256, 0, stream>>>(image, pacc);
  k_mean2<<<256, 256, 0, stream>>>(pacc, meanbf);
  k_gemm_init<<<384, 256, 0, stream>>>(meanbf, wcomb, bh, bm, bih, bhh, vp, Wih,
                                       hbuf, mbuf, basebuf);
  k_basefull<<<4096, 256, 0, stream>>>(labb, wlabb, basebuf, Wih, bfull);
  for (int t = 0; t < 16; ++t) {
    k_step<<<256, 256, 0, stream>>>(hbuf + (size_t)t * 256 * 1024, whhb,
                                    bfull + (size_t)t * 256 * 4096, mbuf,
                                    hbuf + (size_t)(t + 1) * 256 * 1024);
  }
  k_fc<<<1152, 256, 0, stream>>>(hbuf + (size_t)256 * 1024, wfcb, bfc, length, out);
}